// Round 4
// baseline (76.872 us; speedup 1.0000x reference)
//
#include <hip/hip_runtime.h>
#include <hip/hip_bf16.h>

// DLRM forward, bf16-MFMA, double-buffered BK=64 pipeline.
// B=2048, dense 13, emb 26x100000x64, 27 feats -> 351 pairs,
// top MLP 415(->448 pad)->1024->512->256->1 sigmoid.

#define BATCH 2048
#define VOCAB 100000
#define EMB 64
#define NSPARSE 26
#define NFEA 27
#define NPAIR 351
#define RLD 448            // padded R row stride (415 -> 448, %64==0)

typedef __attribute__((ext_vector_type(8))) __bf16 bf16x8;
typedef __attribute__((ext_vector_type(4))) float f32x4;
typedef __hip_bfloat16 bf16;

#define GLOAD16(g, l)                                                          \
    __builtin_amdgcn_global_load_lds(                                          \
        (const __attribute__((address_space(1))) unsigned int*)(g),            \
        (__attribute__((address_space(3))) unsigned int*)(l), 16, 0, 0)

template<int BK>
__device__ __forceinline__ int swz(int row, int s) {
    return (BK == 64) ? (s ^ (row & 7)) : (s ^ ((row >> 1) & 3));
}

// ---------------------------------------------------------------------------
// bf16 MFMA GEMM: C[M,ldC] = relu(A[M,K] @ Wt[N,K]^T + bias), bf16 I/O,
// f32 accum. 64x64 tile / block, 4 waves (2x2 of 32x32), double-buffered LDS.
// Per iter: issue next-tile global_load_lds FIRST, then compute current tile,
// then one __syncthreads() (vmcnt(0) drains loads that flew during compute).
// LDS 16B-slot swizzle (both-sides): BK=64: s^=row&7; BK=32: s^=(row>>1)&3.
// DENSEPAD: A is raw f32 [M][13]; stage+convert+pad to K=32 in-kernel.
// ---------------------------------------------------------------------------
template<int BK, bool DENSEPAD>
__global__ __launch_bounds__(256) void gemm_bf16(
    const void* __restrict__ Araw,  // bf16 [M][K]  (or f32 [M][13] if DENSEPAD)
    const bf16* __restrict__ Wt,    // [N][K] = W^T
    const float* __restrict__ bias,
    bf16* __restrict__ C,           // [M][ldC]
    int M, int N, int K, int ldC)
{
    constexpr int ROWB   = BK * 2;        // bytes per LDS row
    constexpr int SLOTS  = BK / 8;        // 16B slots per row
    constexpr int PASSES = BK / 32;       // global_load_lds passes per matrix
    constexpr int RPP    = 256 / SLOTS;   // rows staged per pass

    __shared__ __align__(16) bf16 As[2][64 * BK];
    __shared__ __align__(16) bf16 Bs[2][64 * BK];

    const int t   = threadIdx.x;
    const int nbn = N >> 6;
    const int bm  = blockIdx.x / nbn;
    const int bn  = blockIdx.x % nbn;
    const int row0 = bm << 6, n0 = bn << 6;

    const int wid  = t >> 6, lane = t & 63;
    const int wr   = wid >> 1, wc = wid & 1;
    const int lr   = lane & 15;
    const int q    = lane >> 4;

    const int srow  = t / SLOTS;
    const int sslot = t % SLOTS;

    const bf16* Ab[PASSES];
    const bf16* Bb[PASSES];
#pragma unroll
    for (int p = 0; p < PASSES; ++p) {
        const int r = p * RPP + srow;
        const int g = swz<BK>(r, sslot);
        if (!DENSEPAD)
            Ab[p] = (const bf16*)Araw + (size_t)(row0 + r) * K + g * 8;
        Bb[p] = Wt + (size_t)(n0 + r) * K + g * 8;
    }

    auto stage = [&](int k0, int buf) {
        if constexpr (DENSEPAD) {
            const float* Df = (const float*)Araw;
#pragma unroll
            for (int idx = t; idx < 64 * 32; idx += 256) {
                const int r = idx >> 5, c = idx & 31;
                const float v = (c < 13) ? Df[(size_t)(row0 + r) * 13 + c] : 0.f;
                As[buf][r * 32 + swz<BK>(r, c >> 3) * 8 + (c & 7)] =
                    __float2bfloat16(v);
            }
        } else {
#pragma unroll
            for (int p = 0; p < PASSES; ++p)
                GLOAD16(Ab[p] + k0, (char*)As[buf] + p * 4096 + t * 16);
        }
#pragma unroll
        for (int p = 0; p < PASSES; ++p)
            GLOAD16(Bb[p] + k0, (char*)Bs[buf] + p * 4096 + t * 16);
    };

    f32x4 acc[2][2] = {};

    stage(0, 0);
    __syncthreads();

    int cur = 0;
    for (int k0 = 0; k0 < K; k0 += BK) {
        if (k0 + BK < K) stage(k0 + BK, cur ^ 1);   // in flight during compute

        bf16x8 af[PASSES][2], bfr[PASSES][2];
#pragma unroll
        for (int kk = 0; kk < PASSES; ++kk) {
#pragma unroll
            for (int m = 0; m < 2; ++m) {
                const int r = wr * 32 + 16 * m + lr;
                af[kk][m] = *(const bf16x8*)((const char*)As[cur] + r * ROWB +
                                             swz<BK>(r, kk * 4 + q) * 16);
            }
#pragma unroll
            for (int n = 0; n < 2; ++n) {
                const int r = wc * 32 + 16 * n + lr;
                bfr[kk][n] = *(const bf16x8*)((const char*)Bs[cur] + r * ROWB +
                                              swz<BK>(r, kk * 4 + q) * 16);
            }
        }
#pragma unroll
        for (int kk = 0; kk < PASSES; ++kk)
#pragma unroll
            for (int m = 0; m < 2; ++m)
#pragma unroll
                for (int n = 0; n < 2; ++n)
                    acc[m][n] = __builtin_amdgcn_mfma_f32_16x16x32_bf16(
                        af[kk][m], bfr[kk][n], acc[m][n], 0, 0, 0);

        __syncthreads();   // vmcnt(0): next-tile loads landed; all waves done
        cur ^= 1;
    }

    // D layout: col = lane&15, row = (lane>>4)*4 + i
#pragma unroll
    for (int n = 0; n < 2; ++n) {
        const int col = n0 + wc * 32 + 16 * n + lr;
        const float bv = bias[col];
#pragma unroll
        for (int m = 0; m < 2; ++m) {
#pragma unroll
            for (int i = 0; i < 4; ++i) {
                const int row = row0 + wr * 32 + 16 * m + q * 4 + i;
                float v = acc[m][n][i] + bv;
                v = fmaxf(v, 0.f);
                C[(size_t)row * ldC + col] = __float2bfloat16(v);
            }
        }
    }
}

// ---------------------------------------------------------------------------
// Weight convert+transpose: dst[n][kp] = bf16(src[k][n]), zero-pad k>=K.
// ---------------------------------------------------------------------------
struct WConvArgs {
    const float* src[6];
    bf16*        dst[6];
    int K[6], N[6], Kp[6], t0[7];
};

__global__ __launch_bounds__(256) void wconv_kernel(WConvArgs a)
{
    __shared__ float Ts[32][33];
    int w = 0;
    while (w < 5 && (int)blockIdx.x >= a.t0[w + 1]) ++w;
    const int rel = blockIdx.x - a.t0[w];
    const int K = a.K[w], N = a.N[w], Kp = a.Kp[w];
    const int nbn = N >> 5;
    const int tk = rel / nbn, tn = rel % nbn;
    const int tx = threadIdx.x & 31, ty = threadIdx.x >> 5;

    const float* src = a.src[w];
    bf16* dst = a.dst[w];

#pragma unroll
    for (int rr = 0; rr < 4; ++rr) {
        const int k = tk * 32 + ty + rr * 8;
        const int n = tn * 32 + tx;
        Ts[ty + rr * 8][tx] = (k < K) ? src[(size_t)k * N + n] : 0.f;
    }
    __syncthreads();
#pragma unroll
    for (int rr = 0; rr < 4; ++rr) {
        const int n = tn * 32 + ty + rr * 8;
        const int kp = tk * 32 + tx;
        dst[(size_t)n * Kp + kp] = __float2bfloat16(Ts[tx][ty + rr * 8]);
    }
}

// ---------------------------------------------------------------------------
// Fused: bot = relu(h1 @ bw2 + bb2)  +  embedding gather  +  pairwise dots.
// 8 batch rows per block, 256 blocks. bot computed on VALU (67 MFLOP total),
// written into LDS T[r][0][:] and R[:, :64]; dots into R[:, 64:415];
// zero-pad R[:, 415:448).
// ---------------------------------------------------------------------------
__global__ __launch_bounds__(256) void interact_kernel(
    const bf16* __restrict__ h1,    // [B][256]
    const bf16* __restrict__ bw2t,  // [64][256] = bw2^T
    const float* __restrict__ bb2,
    const int* __restrict__ cat_idx,
    const float* __restrict__ tables,
    bf16* __restrict__ R)
{
    __shared__ float T[8][NFEA][EMB + 1];   // stride 65: dot reads conflict-free
    __shared__ bf16  h1s[8][256];

    const int b0 = blockIdx.x * 8;
    const int t  = threadIdx.x;

    // stage h1 rows (8 x 256 bf16), 8 elems/thread
    {
        const int r = t >> 5, c = (t & 31) * 8;
        *(bf16x8*)&h1s[r][c] =
            *(const bf16x8*)&h1[(size_t)(b0 + r) * 256 + c];
    }

    // gather embeddings: 8 rows x 26 feats x 16 float4
    for (int l = t; l < 8 * NSPARSE * 16; l += 256) {
        const int pair = l >> 4, c = (l & 15) * 4;
        const int r = pair / NSPARSE, j = pair % NSPARSE;
        const int idx = cat_idx[(b0 + r) * NSPARSE + j];
        const float4 v =
            *(const float4*)&tables[((size_t)j * VOCAB + idx) * EMB + c];
        float* dst = &T[r][j + 1][c];
        dst[0] = v.x; dst[1] = v.y; dst[2] = v.z; dst[3] = v.w;
    }
    __syncthreads();

    // bot: 512 outputs, 2 per thread (r = o>>6, n = o&63)
    for (int o = t; o < 512; o += 256) {
        const int r = o >> 6, n = o & 63;
        float s = bb2[n];
        const bf16* wrow = bw2t + (size_t)n * 256;
        for (int k = 0; k < 256; k += 8) {
            const bf16x8 hv = *(const bf16x8*)&h1s[r][k];
            const bf16x8 wv = *(const bf16x8*)&wrow[k];
#pragma unroll
            for (int u = 0; u < 8; ++u)
                s += (float)hv[u] * (float)wv[u];
        }
        s = fmaxf(s, 0.f);
        T[r][0][n] = s;
        R[(size_t)(b0 + r) * RLD + n] = __float2bfloat16(s);
    }

    // zero-pad R[:, 415:448)
    for (int z = t; z < 8 * (RLD - 415); z += 256) {
        const int r = z / (RLD - 415), c = z % (RLD - 415);
        R[(size_t)(b0 + r) * RLD + 415 + c] = __float2bfloat16(0.f);
    }
    __syncthreads();

    // pairwise dots: 8 x 351 tasks
    for (int task = t; task < 8 * NPAIR; task += 256) {
        const int r = task / NPAIR, p = task % NPAIR;
        int i = (int)((1.0f + sqrtf(1.0f + 8.0f * (float)p)) * 0.5f);
        while (i * (i - 1) / 2 > p) --i;
        while ((i + 1) * i / 2 <= p) ++i;
        const int j = p - i * (i - 1) / 2;
        float s = 0.f;
#pragma unroll 16
        for (int k = 0; k < EMB; ++k) s += T[r][i][k] * T[r][j][k];
        R[(size_t)(b0 + r) * RLD + EMB + p] = __float2bfloat16(s);
    }
}

// final layer: out[b] = sigmoid(dot(r2[b,:256] (bf16), tw3 (f32)) + tb3)
__global__ __launch_bounds__(256) void top3_kernel(
    const bf16* __restrict__ A, const float* __restrict__ w,
    const float* __restrict__ bias, float* __restrict__ out)
{
    const int gid  = blockIdx.x * 256 + threadIdx.x;
    const int row  = gid >> 6;
    const int lane = gid & 63;

    const bf16* arow = A + (size_t)row * 256;
    float s = 0.f;
#pragma unroll
    for (int k = lane; k < 256; k += 64)
        s += __bfloat162float(arow[k]) * w[k];
#pragma unroll
    for (int off = 32; off; off >>= 1) s += __shfl_down(s, off);
    if (lane == 0) out[row] = 1.f / (1.f + expf(-(s + bias[0])));
}

// ---------------------------------------------------------------------------
extern "C" void kernel_launch(void* const* d_in, const int* in_sizes, int n_in,
                              void* d_out, int out_size, void* d_ws, size_t ws_size,
                              hipStream_t stream)
{
    const float* dense   = (const float*)d_in[0];
    const int*   cat_idx = (const int*)  d_in[1];
    const float* tables  = (const float*)d_in[2];
    const float* bw0 = (const float*)d_in[3];
    const float* bb0 = (const float*)d_in[4];
    const float* bw1 = (const float*)d_in[5];
    const float* bb1 = (const float*)d_in[6];
    const float* bw2 = (const float*)d_in[7];
    const float* bb2 = (const float*)d_in[8];
    const float* tw0 = (const float*)d_in[9];
    const float* tb0 = (const float*)d_in[10];
    const float* tw1 = (const float*)d_in[11];
    const float* tb1 = (const float*)d_in[12];
    const float* tw2 = (const float*)d_in[13];
    const float* tb2 = (const float*)d_in[14];
    const float* tw3 = (const float*)d_in[15];
    const float* tb3 = (const float*)d_in[16];

    bf16* p = (bf16*)d_ws;
    bf16* h0   = p; p += (size_t)BATCH * 512;
    bf16* h1   = p; p += (size_t)BATCH * 256;
    bf16* R    = p; p += (size_t)BATCH * RLD;
    bf16* r0   = p; p += (size_t)BATCH * 1024;
    bf16* r1   = p; p += (size_t)BATCH * 512;
    bf16* r2   = p; p += (size_t)BATCH * 256;
    bf16* bw0t = p; p += 512 * 32;
    bf16* bw1t = p; p += 256 * 512;
    bf16* bw2t = p; p += 64 * 256;
    bf16* tw0t = p; p += 1024 * RLD;
    bf16* tw1t = p; p += 512 * 1024;
    bf16* tw2t = p; p += 256 * 512;
    float* out = (float*)d_out;

    WConvArgs wa;
    wa.src[0] = bw0;  wa.dst[0] = bw0t; wa.K[0] = 13;   wa.N[0] = 512;  wa.Kp[0] = 32;
    wa.src[1] = bw1;  wa.dst[1] = bw1t; wa.K[1] = 512;  wa.N[1] = 256;  wa.Kp[1] = 512;
    wa.src[2] = bw2;  wa.dst[2] = bw2t; wa.K[2] = 256;  wa.N[2] = 64;   wa.Kp[2] = 256;
    wa.src[3] = tw0;  wa.dst[3] = tw0t; wa.K[3] = 415;  wa.N[3] = 1024; wa.Kp[3] = RLD;
    wa.src[4] = tw1;  wa.dst[4] = tw1t; wa.K[4] = 1024; wa.N[4] = 512;  wa.Kp[4] = 1024;
    wa.src[5] = tw2;  wa.dst[5] = tw2t; wa.K[5] = 512;  wa.N[5] = 256;  wa.Kp[5] = 512;
    int tiles = 0;
    for (int w = 0; w < 6; ++w) {
        wa.t0[w] = tiles;
        tiles += (wa.Kp[w] >> 5) * (wa.N[w] >> 5);
    }
    wa.t0[6] = tiles;

    wconv_kernel<<<tiles, 256, 0, stream>>>(wa);

    // bottom MLP (layer 0 fused: f32 dense staged+padded in-kernel)
    gemm_bf16<32, true ><<<(BATCH / 64) * (512 / 64), 256, 0, stream>>>(
        dense, bw0t, bb0, h0, BATCH, 512, 32, 512);
    gemm_bf16<64, false><<<(BATCH / 64) * (256 / 64), 256, 0, stream>>>(
        h0, bw1t, bb1, h1, BATCH, 256, 512, 256);

    // bot (h1 @ bw2) + gather + interaction, fused
    interact_kernel<<<BATCH / 8, 256, 0, stream>>>(
        h1, bw2t, bb2, cat_idx, tables, R);

    // top MLP
    gemm_bf16<64, false><<<(BATCH / 64) * (1024 / 64), 256, 0, stream>>>(
        R, tw0t, tb0, r0, BATCH, 1024, RLD, 1024);
    gemm_bf16<64, false><<<(BATCH / 64) * (512 / 64), 256, 0, stream>>>(
        r0, tw1t, tb1, r1, BATCH, 512, 1024, 512);
    gemm_bf16<64, false><<<(BATCH / 64) * (256 / 64), 256, 0, stream>>>(
        r1, tw2t, tb2, r2, BATCH, 256, 512, 256);
    top3_kernel<<<BATCH / 4, 256, 0, stream>>>(r2, tw3, tb3, out);
}

// Round 5
// 70.294 us; speedup vs baseline: 1.0936x; 1.0936x over previous
//
#include <hip/hip_runtime.h>
#include <hip/hip_bf16.h>

// DLRM forward, bf16-MFMA. B=2048, dense 13, emb 26x100000x64,
// 27 feats -> 351 pairs, top MLP 415(->448)->1024->512->256->1 sigmoid.

#define BATCH 2048
#define VOCAB 100000
#define EMB 64
#define NSPARSE 26
#define NFEA 27
#define NPAIR 351
#define RLD 448            // padded R row stride (415 -> 448, %64==0)

typedef __attribute__((ext_vector_type(8))) __bf16 bf16x8;
typedef __attribute__((ext_vector_type(4))) float f32x4;
typedef __hip_bfloat16 bf16;

#define GLOAD16(g, l)                                                          \
    __builtin_amdgcn_global_load_lds(                                          \
        (const __attribute__((address_space(1))) unsigned int*)(g),            \
        (__attribute__((address_space(3))) unsigned int*)(l), 16, 0, 0)

template<int BK>
__device__ __forceinline__ int swz(int row, int s) {
    return (BK == 64) ? (s ^ (row & 7)) : (s ^ ((row >> 1) & 3));
}

// ---------------------------------------------------------------------------
// bf16 MFMA GEMM: C[M,ldC] = relu(A[M,K] @ Wt[N,K]^T + bias), bf16 I/O,
// f32 accum. 256 thr = 4 waves arranged WR x WC; each wave computes a
// (MREP*16) x (NREP*16) sub-tile via 16x16x32 MFMA. Block = BM x BN where
// BM = WR*MREP*16, BN = WC*NREP*16. Single-buffered LDS, 16B-slot swizzle
// (both sides): BK=64: s^=row&7; BK=32: s^=(row>>1)&3.
// DENSEPAD: A is raw f32 [M][13]; stage+convert+pad to K=32 in-kernel.
// ---------------------------------------------------------------------------
template<int BK, int WR, int WC, int MREP, int NREP, bool DENSEPAD>
__global__ __launch_bounds__(256) void gemm_bf16(
    const void* __restrict__ Araw,  // bf16 [M][K]  (or f32 [M][13] if DENSEPAD)
    const bf16* __restrict__ Wt,    // [N][K] = W^T
    const float* __restrict__ bias,
    bf16* __restrict__ C,           // [M][ldC]
    int M, int N, int K, int ldC)
{
    constexpr int BM    = WR * MREP * 16;
    constexpr int BN    = WC * NREP * 16;
    constexpr int ROWB  = BK * 2;          // bytes per LDS row
    constexpr int SLOTS = BK / 8;          // 16B slots per row
    constexpr int KKS   = BK / 32;         // 32-k sub-steps per iter
    constexpr int PA    = BM * SLOTS / 256;
    constexpr int PB    = BN * SLOTS / 256;

    __shared__ __align__(16) bf16 As[BM * BK];
    __shared__ __align__(16) bf16 Bs[BN * BK];

    const int t   = threadIdx.x;
    const int nbn = N / BN;
    const int bm  = blockIdx.x / nbn;
    const int bn  = blockIdx.x % nbn;
    const int row0 = bm * BM, n0 = bn * BN;

    const int wid  = t >> 6, lane = t & 63;
    const int wr   = wid / WC, wc = wid % WC;
    const int lr   = lane & 15;
    const int q    = lane >> 4;

    const int sslot = t % SLOTS;

    const bf16* Ab[PA];
    const bf16* Bb[PB];
#pragma unroll
    for (int p = 0; p < PA; ++p) {
        const int r = (p * 256 + t) / SLOTS;
        if (!DENSEPAD)
            Ab[p] = (const bf16*)Araw + (size_t)(row0 + r) * K +
                    swz<BK>(r, sslot) * 8;
    }
#pragma unroll
    for (int p = 0; p < PB; ++p) {
        const int r = (p * 256 + t) / SLOTS;
        Bb[p] = Wt + (size_t)(n0 + r) * K + swz<BK>(r, sslot) * 8;
    }

    f32x4 acc[MREP][NREP] = {};

    for (int k0 = 0; k0 < K; k0 += BK) {
        if constexpr (DENSEPAD) {
            const float* Df = (const float*)Araw;
#pragma unroll
            for (int idx = t; idx < BM * 32; idx += 256) {
                const int r = idx >> 5, c = idx & 31;
                const float v = (c < 13) ? Df[(size_t)(row0 + r) * 13 + c] : 0.f;
                As[r * 32 + swz<BK>(r, c >> 3) * 8 + (c & 7)] =
                    __float2bfloat16(v);
            }
        } else {
#pragma unroll
            for (int p = 0; p < PA; ++p)
                GLOAD16(Ab[p] + k0, (char*)As + (p * 256 + t) * 16);
        }
#pragma unroll
        for (int p = 0; p < PB; ++p)
            GLOAD16(Bb[p] + k0, (char*)Bs + (p * 256 + t) * 16);
        __syncthreads();

        bf16x8 af[KKS][MREP], bfr[KKS][NREP];
#pragma unroll
        for (int kk = 0; kk < KKS; ++kk) {
#pragma unroll
            for (int m = 0; m < MREP; ++m) {
                const int r = wr * MREP * 16 + 16 * m + lr;
                af[kk][m] = *(const bf16x8*)((const char*)As + r * ROWB +
                                             swz<BK>(r, kk * 4 + q) * 16);
            }
#pragma unroll
            for (int n = 0; n < NREP; ++n) {
                const int r = wc * NREP * 16 + 16 * n + lr;
                bfr[kk][n] = *(const bf16x8*)((const char*)Bs + r * ROWB +
                                              swz<BK>(r, kk * 4 + q) * 16);
            }
        }
#pragma unroll
        for (int kk = 0; kk < KKS; ++kk)
#pragma unroll
            for (int m = 0; m < MREP; ++m)
#pragma unroll
                for (int n = 0; n < NREP; ++n)
                    acc[m][n] = __builtin_amdgcn_mfma_f32_16x16x32_bf16(
                        af[kk][m], bfr[kk][n], acc[m][n], 0, 0, 0);
        __syncthreads();
    }

    // D layout: col = lane&15, row = (lane>>4)*4 + i
#pragma unroll
    for (int n = 0; n < NREP; ++n) {
        const int col = n0 + wc * NREP * 16 + 16 * n + lr;
        const float bv = bias[col];
#pragma unroll
        for (int m = 0; m < MREP; ++m) {
#pragma unroll
            for (int i = 0; i < 4; ++i) {
                const int row = row0 + wr * MREP * 16 + 16 * m + q * 4 + i;
                float v = acc[m][n][i] + bv;
                v = fmaxf(v, 0.f);
                C[(size_t)row * ldC + col] = __float2bfloat16(v);
            }
        }
    }
}

// ---------------------------------------------------------------------------
// Weight convert+transpose: dst[n][kp] = bf16(src[k][n]), zero-pad k>=K.
// ---------------------------------------------------------------------------
struct WConvArgs {
    const float* src[6];
    bf16*        dst[6];
    int K[6], N[6], Kp[6], t0[7];
};

__global__ __launch_bounds__(256) void wconv_kernel(WConvArgs a)
{
    __shared__ float Ts[32][33];
    int w = 0;
    while (w < 5 && (int)blockIdx.x >= a.t0[w + 1]) ++w;
    const int rel = blockIdx.x - a.t0[w];
    const int K = a.K[w], N = a.N[w], Kp = a.Kp[w];
    const int nbn = N >> 5;
    const int tk = rel / nbn, tn = rel % nbn;
    const int tx = threadIdx.x & 31, ty = threadIdx.x >> 5;

    const float* src = a.src[w];
    bf16* dst = a.dst[w];

#pragma unroll
    for (int rr = 0; rr < 4; ++rr) {
        const int k = tk * 32 + ty + rr * 8;
        const int n = tn * 32 + tx;
        Ts[ty + rr * 8][tx] = (k < K) ? src[(size_t)k * N + n] : 0.f;
    }
    __syncthreads();
#pragma unroll
    for (int rr = 0; rr < 4; ++rr) {
        const int n = tn * 32 + ty + rr * 8;
        const int kp = tk * 32 + tx;
        dst[(size_t)n * Kp + kp] = __float2bfloat16(Ts[tx][ty + rr * 8]);
    }
}

// ---------------------------------------------------------------------------
// Fused: bot = relu(h1 @ bw2 + bb2) + embedding gather + pairwise dots.
// 2 batch rows per block, 1024 blocks, ~15 KB LDS (keeps gather occupancy).
// ---------------------------------------------------------------------------
__global__ __launch_bounds__(256) void interact_kernel(
    const bf16* __restrict__ h1,    // [B][256]
    const bf16* __restrict__ bw2t,  // [64][256] = bw2^T
    const float* __restrict__ bb2,
    const int* __restrict__ cat_idx,
    const float* __restrict__ tables,
    bf16* __restrict__ R)
{
    __shared__ float T[2][NFEA][EMB + 1];   // stride 65: conflict-free dots
    __shared__ bf16  h1s[2][256];

    const int b0 = blockIdx.x * 2;
    const int t  = threadIdx.x;

    // stage h1 rows (2 x 256 bf16): 64 threads x bf16x8
    if (t < 64) {
        const int r = t >> 5, c = (t & 31) * 8;
        *(bf16x8*)&h1s[r][c] =
            *(const bf16x8*)&h1[(size_t)(b0 + r) * 256 + c];
    }

    // gather embeddings: 2 rows x 26 feats x 16 float4 = 832 loads
    for (int l = t; l < 2 * NSPARSE * 16; l += 256) {
        const int r   = l / (NSPARSE * 16);
        const int rem = l % (NSPARSE * 16);
        const int j   = rem >> 4, c = (rem & 15) * 4;
        const int idx = cat_idx[(b0 + r) * NSPARSE + j];
        const float4 v =
            *(const float4*)&tables[((size_t)j * VOCAB + idx) * EMB + c];
        float* dst = &T[r][j + 1][c];
        dst[0] = v.x; dst[1] = v.y; dst[2] = v.z; dst[3] = v.w;
    }

    // zero-pad R[:, 415:448)
    for (int z = t; z < 2 * (RLD - 415); z += 256) {
        const int r = z / (RLD - 415), c = z % (RLD - 415);
        R[(size_t)(b0 + r) * RLD + 415 + c] = __float2bfloat16(0.f);
    }
    __syncthreads();

    // bot: 128 outputs, 1 per thread for t<128 (r = t>>6, n = t&63)
    if (t < 128) {
        const int r = t >> 6, n = t & 63;
        float s = bb2[n];
        const bf16* wrow = bw2t + (size_t)n * 256;
#pragma unroll 8
        for (int k = 0; k < 256; k += 8) {
            const bf16x8 hv = *(const bf16x8*)&h1s[r][k];
            const bf16x8 wv = *(const bf16x8*)&wrow[k];
#pragma unroll
            for (int u = 0; u < 8; ++u)
                s += (float)hv[u] * (float)wv[u];
        }
        s = fmaxf(s, 0.f);
        T[r][0][n] = s;
        R[(size_t)(b0 + r) * RLD + n] = __float2bfloat16(s);
    }
    __syncthreads();

    // pairwise dots: 2 x 351 tasks
    for (int task = t; task < 2 * NPAIR; task += 256) {
        const int r = task / NPAIR, p = task % NPAIR;
        int i = (int)((1.0f + sqrtf(1.0f + 8.0f * (float)p)) * 0.5f);
        while (i * (i - 1) / 2 > p) --i;
        while ((i + 1) * i / 2 <= p) ++i;
        const int j = p - i * (i - 1) / 2;
        float s = 0.f;
#pragma unroll 16
        for (int k = 0; k < EMB; ++k) s += T[r][i][k] * T[r][j][k];
        R[(size_t)(b0 + r) * RLD + EMB + p] = __float2bfloat16(s);
    }
}

// final layer: out[b] = sigmoid(dot(r2[b,:256] (bf16), tw3 (f32)) + tb3)
__global__ __launch_bounds__(256) void top3_kernel(
    const bf16* __restrict__ A, const float* __restrict__ w,
    const float* __restrict__ bias, float* __restrict__ out)
{
    const int gid  = blockIdx.x * 256 + threadIdx.x;
    const int row  = gid >> 6;
    const int lane = gid & 63;

    const bf16* arow = A + (size_t)row * 256;
    float s = 0.f;
#pragma unroll
    for (int k = lane; k < 256; k += 64)
        s += __bfloat162float(arow[k]) * w[k];
#pragma unroll
    for (int off = 32; off; off >>= 1) s += __shfl_down(s, off);
    if (lane == 0) out[row] = 1.f / (1.f + expf(-(s + bias[0])));
}

// ---------------------------------------------------------------------------
extern "C" void kernel_launch(void* const* d_in, const int* in_sizes, int n_in,
                              void* d_out, int out_size, void* d_ws, size_t ws_size,
                              hipStream_t stream)
{
    const float* dense   = (const float*)d_in[0];
    const int*   cat_idx = (const int*)  d_in[1];
    const float* tables  = (const float*)d_in[2];
    const float* bw0 = (const float*)d_in[3];
    const float* bb0 = (const float*)d_in[4];
    const float* bw1 = (const float*)d_in[5];
    const float* bb1 = (const float*)d_in[6];
    const float* bw2 = (const float*)d_in[7];
    const float* bb2 = (const float*)d_in[8];
    const float* tw0 = (const float*)d_in[9];
    const float* tb0 = (const float*)d_in[10];
    const float* tw1 = (const float*)d_in[11];
    const float* tb1 = (const float*)d_in[12];
    const float* tw2 = (const float*)d_in[13];
    const float* tb2 = (const float*)d_in[14];
    const float* tw3 = (const float*)d_in[15];
    const float* tb3 = (const float*)d_in[16];

    bf16* p = (bf16*)d_ws;
    bf16* h0   = p; p += (size_t)BATCH * 512;
    bf16* h1   = p; p += (size_t)BATCH * 256;
    bf16* R    = p; p += (size_t)BATCH * RLD;
    bf16* r0   = p; p += (size_t)BATCH * 1024;
    bf16* r1   = p; p += (size_t)BATCH * 512;
    bf16* r2   = p; p += (size_t)BATCH * 256;
    bf16* bw0t = p; p += 512 * 32;
    bf16* bw1t = p; p += 256 * 512;
    bf16* bw2t = p; p += 64 * 256;
    bf16* tw0t = p; p += 1024 * RLD;
    bf16* tw1t = p; p += 512 * 1024;
    bf16* tw2t = p; p += 256 * 512;
    float* out = (float*)d_out;

    WConvArgs wa;
    wa.src[0] = bw0;  wa.dst[0] = bw0t; wa.K[0] = 13;   wa.N[0] = 512;  wa.Kp[0] = 32;
    wa.src[1] = bw1;  wa.dst[1] = bw1t; wa.K[1] = 512;  wa.N[1] = 256;  wa.Kp[1] = 512;
    wa.src[2] = bw2;  wa.dst[2] = bw2t; wa.K[2] = 256;  wa.N[2] = 64;   wa.Kp[2] = 256;
    wa.src[3] = tw0;  wa.dst[3] = tw0t; wa.K[3] = 415;  wa.N[3] = 1024; wa.Kp[3] = RLD;
    wa.src[4] = tw1;  wa.dst[4] = tw1t; wa.K[4] = 1024; wa.N[4] = 512;  wa.Kp[4] = 1024;
    wa.src[5] = tw2;  wa.dst[5] = tw2t; wa.K[5] = 512;  wa.N[5] = 256;  wa.Kp[5] = 512;
    int tiles = 0;
    for (int w = 0; w < 6; ++w) {
        wa.t0[w] = tiles;
        tiles += (wa.Kp[w] >> 5) * (wa.N[w] >> 5);
    }
    wa.t0[6] = tiles;

    wconv_kernel<<<tiles, 256, 0, stream>>>(wa);

    // bottom MLP (layer 0: f32 dense staged+padded in-kernel; 64x64 tiles)
    gemm_bf16<32, 2, 2, 2, 2, true ><<<(BATCH / 64) * (512 / 64), 256, 0, stream>>>(
        dense, bw0t, bb0, h0, BATCH, 512, 32, 512);
    gemm_bf16<64, 2, 2, 2, 2, false><<<(BATCH / 64) * (256 / 64), 256, 0, stream>>>(
        h0, bw1t, bb1, h1, BATCH, 256, 512, 256);

    // bot (h1 @ bw2) + gather + interaction, fused; 2 rows/block
    interact_kernel<<<BATCH / 2, 256, 0, stream>>>(
        h1, bw2t, bb2, cat_idx, tables, R);

    // top MLP: top0 uses 128x64 tiles (wave 32x64, acc[2][4] — 6 ds_read : 8 MFMA)
    gemm_bf16<64, 4, 1, 2, 4, false><<<(BATCH / 128) * (1024 / 64), 256, 0, stream>>>(
        R, tw0t, tb0, r0, BATCH, 1024, RLD, 1024);
    gemm_bf16<64, 2, 2, 2, 2, false><<<(BATCH / 64) * (512 / 64), 256, 0, stream>>>(
        r0, tw1t, tb1, r1, BATCH, 512, 1024, 512);
    gemm_bf16<64, 2, 2, 2, 2, false><<<(BATCH / 64) * (256 / 64), 256, 0, stream>>>(
        r1, tw2t, tb2, r2, BATCH, 256, 512, 256);
    top3_kernel<<<BATCH / 4, 256, 0, stream>>>(r2, tw3, tb3, out);
}

// Round 6
// 66.971 us; speedup vs baseline: 1.1478x; 1.0496x over previous
//
#include <hip/hip_runtime.h>
#include <hip/hip_bf16.h>

// DLRM forward, bf16-MFMA, depth-2 counted-vmcnt pipelined GEMM.
// B=2048, dense 13, emb 26x100000x64, 27 feats -> 351 pairs,
// top MLP 415(->448)->1024->512->256->1 sigmoid.

#define BATCH 2048
#define VOCAB 100000
#define EMB 64
#define NSPARSE 26
#define NFEA 27
#define NPAIR 351
#define RLD 448            // padded R row stride (415 -> 448, %64==0)

typedef __attribute__((ext_vector_type(8))) __bf16 bf16x8;
typedef __attribute__((ext_vector_type(4))) float f32x4;
typedef __hip_bfloat16 bf16;

#define GLOAD16(g, l)                                                          \
    __builtin_amdgcn_global_load_lds(                                          \
        (const __attribute__((address_space(1))) unsigned int*)(g),            \
        (__attribute__((address_space(3))) unsigned int*)(l), 16, 0, 0)

template<int BK>
__device__ __forceinline__ int swz(int row, int s) {
    return (BK == 64) ? (s ^ (row & 7)) : (s ^ ((row >> 1) & 3));
}

// ---------------------------------------------------------------------------
// bf16 MFMA GEMM: C[M,ldC] = relu(A[M,K] @ Wt[N,K]^T + bias), bf16 I/O,
// f32 accum. 4 waves (WR x WC), wave sub-tile (MREP*16) x (NREP*16).
// Pipelined path (!DENSEPAD): BK=64, 3 LDS buffers, depth-2 prefetch.
// Per iter: stage(k+2) [4 global_load_lds/thread, tail-clamped so in-flight
// is constant]; s_waitcnt vmcnt(8) -> tile-k loads landed; raw s_barrier;
// ds_read+MFMA on buf[k%3]; lgkmcnt(0) + raw s_barrier (buffer-reuse guard).
// vmcnt NEVER drains to 0 in-loop (T4). 16B-slot swizzle both sides.
// DENSEPAD: A raw f32 [M][13], K=32 single step, simple path.
// ---------------------------------------------------------------------------
template<int BK, int WR, int WC, int MREP, int NREP, bool DENSEPAD>
__global__ __launch_bounds__(256) void gemm_bf16(
    const void* __restrict__ Araw,  // bf16 [M][K]  (or f32 [M][13] if DENSEPAD)
    const bf16* __restrict__ Wt,    // [N][K] = W^T
    const float* __restrict__ bias,
    bf16* __restrict__ C,           // [M][ldC]
    int M, int N, int K, int ldC)
{
    constexpr int BM    = WR * MREP * 16;
    constexpr int BN    = WC * NREP * 16;
    constexpr int ROWB  = BK * 2;          // bytes per LDS row
    constexpr int SLOTS = BK / 8;          // 16B slots per row
    constexpr int KKS   = BK / 32;         // 32-k sub-steps per iter
    constexpr int PA    = BM * SLOTS / 256;
    constexpr int PB    = BN * SLOTS / 256;

    const int t   = threadIdx.x;
    const int nbn = N / BN;
    const int bm  = blockIdx.x / nbn;
    const int bn  = blockIdx.x % nbn;
    const int row0 = bm * BM, n0 = bn * BN;

    const int wid  = t >> 6, lane = t & 63;
    const int wr   = wid / WC, wc = wid % WC;
    const int lr   = lane & 15;
    const int q    = lane >> 4;
    const int sslot = t % SLOTS;

    f32x4 acc[MREP][NREP] = {};

    if constexpr (DENSEPAD) {
        // ---- single K-step (K=32): VALU-stage A (f32->bf16 pad), async B ----
        __shared__ __align__(16) bf16 As[BM * BK];
        __shared__ __align__(16) bf16 Bs[BN * BK];

        const float* Df = (const float*)Araw;
#pragma unroll
        for (int p = 0; p < PB; ++p) {
            const int r = (p * 256 + t) / SLOTS;
            GLOAD16(Wt + (size_t)(n0 + r) * K + swz<BK>(r, sslot) * 8,
                    (char*)Bs + (p * 256 + t) * 16);
        }
#pragma unroll
        for (int idx = t; idx < BM * 32; idx += 256) {
            const int r = idx >> 5, c = idx & 31;
            const float v = (c < 13) ? Df[(size_t)(row0 + r) * 13 + c] : 0.f;
            As[r * 32 + swz<BK>(r, c >> 3) * 8 + (c & 7)] = __float2bfloat16(v);
        }
        __syncthreads();

        bf16x8 af[KKS][MREP], bfr[KKS][NREP];
#pragma unroll
        for (int kk = 0; kk < KKS; ++kk) {
#pragma unroll
            for (int m = 0; m < MREP; ++m) {
                const int r = wr * MREP * 16 + 16 * m + lr;
                af[kk][m] = *(const bf16x8*)((const char*)As + r * ROWB +
                                             swz<BK>(r, kk * 4 + q) * 16);
            }
#pragma unroll
            for (int n = 0; n < NREP; ++n) {
                const int r = wc * NREP * 16 + 16 * n + lr;
                bfr[kk][n] = *(const bf16x8*)((const char*)Bs + r * ROWB +
                                              swz<BK>(r, kk * 4 + q) * 16);
            }
        }
#pragma unroll
        for (int kk = 0; kk < KKS; ++kk)
#pragma unroll
            for (int m = 0; m < MREP; ++m)
#pragma unroll
                for (int n = 0; n < NREP; ++n)
                    acc[m][n] = __builtin_amdgcn_mfma_f32_16x16x32_bf16(
                        af[kk][m], bfr[kk][n], acc[m][n], 0, 0, 0);
    } else {
        // ---- depth-2 counted-vmcnt pipeline, 3 buffers ----
        static_assert(PA + PB == 4, "vmcnt immediate assumes 4 loads/thread");
        __shared__ __align__(16) bf16 As[3][BM * BK];
        __shared__ __align__(16) bf16 Bs[3][BN * BK];

        const bf16* Ab[PA];
        const bf16* Bb[PB];
#pragma unroll
        for (int p = 0; p < PA; ++p) {
            const int r = (p * 256 + t) / SLOTS;
            Ab[p] = (const bf16*)Araw + (size_t)(row0 + r) * K +
                    swz<BK>(r, sslot) * 8;
        }
#pragma unroll
        for (int p = 0; p < PB; ++p) {
            const int r = (p * 256 + t) / SLOTS;
            Bb[p] = Wt + (size_t)(n0 + r) * K + swz<BK>(r, sslot) * 8;
        }

        const int nsteps = K / BK;
        auto stage = [&](int s) {   // s may exceed nsteps-1: clamp k, dead buf
            const int buf = s % 3;
            const int k0  = (s < nsteps ? s : nsteps - 1) * BK;
#pragma unroll
            for (int p = 0; p < PA; ++p)
                GLOAD16(Ab[p] + k0, (char*)As[buf] + (p * 256 + t) * 16);
#pragma unroll
            for (int p = 0; p < PB; ++p)
                GLOAD16(Bb[p] + k0, (char*)Bs[buf] + (p * 256 + t) * 16);
        };

        stage(0);
        stage(1);

        for (int ks = 0; ks < nsteps; ++ks) {
            stage(ks + 2);                      // in flight during compute(ks)

            asm volatile("s_waitcnt vmcnt(8)" ::: "memory");  // tile ks landed
            __builtin_amdgcn_s_barrier();
            __builtin_amdgcn_sched_barrier(0);

            const int buf = ks % 3;
            bf16x8 af[KKS][MREP], bfr[KKS][NREP];
#pragma unroll
            for (int kk = 0; kk < KKS; ++kk) {
#pragma unroll
                for (int m = 0; m < MREP; ++m) {
                    const int r = wr * MREP * 16 + 16 * m + lr;
                    af[kk][m] = *(const bf16x8*)((const char*)As[buf] + r * ROWB +
                                                 swz<BK>(r, kk * 4 + q) * 16);
                }
#pragma unroll
                for (int n = 0; n < NREP; ++n) {
                    const int r = wc * NREP * 16 + 16 * n + lr;
                    bfr[kk][n] = *(const bf16x8*)((const char*)Bs[buf] + r * ROWB +
                                                  swz<BK>(r, kk * 4 + q) * 16);
                }
            }
#pragma unroll
            for (int kk = 0; kk < KKS; ++kk)
#pragma unroll
                for (int m = 0; m < MREP; ++m)
#pragma unroll
                    for (int n = 0; n < NREP; ++n)
                        acc[m][n] = __builtin_amdgcn_mfma_f32_16x16x32_bf16(
                            af[kk][m], bfr[kk][n], acc[m][n], 0, 0, 0);

            asm volatile("s_waitcnt lgkmcnt(0)" ::: "memory");
            __builtin_amdgcn_s_barrier();       // buf[ks%3] free for ks+3 stage
            __builtin_amdgcn_sched_barrier(0);
        }
    }

    // D layout: col = lane&15, row = (lane>>4)*4 + i
#pragma unroll
    for (int n = 0; n < NREP; ++n) {
        const int col = n0 + wc * NREP * 16 + 16 * n + lr;
        const float bv = bias[col];
#pragma unroll
        for (int m = 0; m < MREP; ++m) {
#pragma unroll
            for (int i = 0; i < 4; ++i) {
                const int row = row0 + wr * MREP * 16 + 16 * m + q * 4 + i;
                float v = acc[m][n][i] + bv;
                v = fmaxf(v, 0.f);
                C[(size_t)row * ldC + col] = __float2bfloat16(v);
            }
        }
    }
}

// ---------------------------------------------------------------------------
// Weight convert+transpose: dst[n][kp] = bf16(src[k][n]), zero-pad k>=K.
// ---------------------------------------------------------------------------
struct WConvArgs {
    const float* src[6];
    bf16*        dst[6];
    int K[6], N[6], Kp[6], t0[7];
};

__global__ __launch_bounds__(256) void wconv_kernel(WConvArgs a)
{
    __shared__ float Ts[32][33];
    int w = 0;
    while (w < 5 && (int)blockIdx.x >= a.t0[w + 1]) ++w;
    const int rel = blockIdx.x - a.t0[w];
    const int K = a.K[w], N = a.N[w], Kp = a.Kp[w];
    const int nbn = N >> 5;
    const int tk = rel / nbn, tn = rel % nbn;
    const int tx = threadIdx.x & 31, ty = threadIdx.x >> 5;

    const float* src = a.src[w];
    bf16* dst = a.dst[w];

#pragma unroll
    for (int rr = 0; rr < 4; ++rr) {
        const int k = tk * 32 + ty + rr * 8;
        const int n = tn * 32 + tx;
        Ts[ty + rr * 8][tx] = (k < K) ? src[(size_t)k * N + n] : 0.f;
    }
    __syncthreads();
#pragma unroll
    for (int rr = 0; rr < 4; ++rr) {
        const int n = tn * 32 + ty + rr * 8;
        const int kp = tk * 32 + tx;
        dst[(size_t)n * Kp + kp] = __float2bfloat16(Ts[tx][ty + rr * 8]);
    }
}

// ---------------------------------------------------------------------------
// Embedding gather + pairwise dots. One block per batch row (R3 form).
// bot (bf16) sits in R[b][0:64]; writes R[b][64+p], zero-pads [415,448).
// ---------------------------------------------------------------------------
__global__ __launch_bounds__(256) void interact_kernel(
    const int* __restrict__ cat_idx, const float* __restrict__ tables,
    bf16* __restrict__ R)
{
    __shared__ float T[NFEA][EMB + 1];

    const int b    = blockIdx.x;
    const int t    = threadIdx.x;
    const int g    = t >> 6;
    const int lane = t & 63;
    bf16* Rrow = R + (size_t)b * RLD;

    for (int f = g; f < NFEA; f += 4) {
        if (f == 0) {
            T[0][lane] = __bfloat162float(Rrow[lane]);
        } else {
            const int j   = f - 1;
            const int idx = cat_idx[b * NSPARSE + j];
            T[f][lane] = tables[((size_t)j * VOCAB + idx) * EMB + lane];
        }
    }
    __syncthreads();

    if (t < RLD - 415) Rrow[415 + t] = __float2bfloat16(0.f);

    for (int p = t; p < NPAIR; p += 256) {
        int i = (int)((1.0f + sqrtf(1.0f + 8.0f * (float)p)) * 0.5f);
        while (i * (i - 1) / 2 > p) --i;
        while ((i + 1) * i / 2 <= p) ++i;
        const int j = p - i * (i - 1) / 2;
        float s = 0.f;
#pragma unroll 16
        for (int k = 0; k < EMB; ++k) s += T[i][k] * T[j][k];
        Rrow[EMB + p] = __float2bfloat16(s);
    }
}

// final layer: out[b] = sigmoid(dot(r2[b,:256] (bf16), tw3 (f32)) + tb3)
__global__ __launch_bounds__(256) void top3_kernel(
    const bf16* __restrict__ A, const float* __restrict__ w,
    const float* __restrict__ bias, float* __restrict__ out)
{
    const int gid  = blockIdx.x * 256 + threadIdx.x;
    const int row  = gid >> 6;
    const int lane = gid & 63;

    const bf16* arow = A + (size_t)row * 256;
    float s = 0.f;
#pragma unroll
    for (int k = lane; k < 256; k += 64)
        s += __bfloat162float(arow[k]) * w[k];
#pragma unroll
    for (int off = 32; off; off >>= 1) s += __shfl_down(s, off);
    if (lane == 0) out[row] = 1.f / (1.f + expf(-(s + bias[0])));
}

// ---------------------------------------------------------------------------
extern "C" void kernel_launch(void* const* d_in, const int* in_sizes, int n_in,
                              void* d_out, int out_size, void* d_ws, size_t ws_size,
                              hipStream_t stream)
{
    const float* dense   = (const float*)d_in[0];
    const int*   cat_idx = (const int*)  d_in[1];
    const float* tables  = (const float*)d_in[2];
    const float* bw0 = (const float*)d_in[3];
    const float* bb0 = (const float*)d_in[4];
    const float* bw1 = (const float*)d_in[5];
    const float* bb1 = (const float*)d_in[6];
    const float* bw2 = (const float*)d_in[7];
    const float* bb2 = (const float*)d_in[8];
    const float* tw0 = (const float*)d_in[9];
    const float* tb0 = (const float*)d_in[10];
    const float* tw1 = (const float*)d_in[11];
    const float* tb1 = (const float*)d_in[12];
    const float* tw2 = (const float*)d_in[13];
    const float* tb2 = (const float*)d_in[14];
    const float* tw3 = (const float*)d_in[15];
    const float* tb3 = (const float*)d_in[16];

    bf16* p = (bf16*)d_ws;
    bf16* h0   = p; p += (size_t)BATCH * 512;
    bf16* h1   = p; p += (size_t)BATCH * 256;
    bf16* R    = p; p += (size_t)BATCH * RLD;
    bf16* r0   = p; p += (size_t)BATCH * 1024;
    bf16* r1   = p; p += (size_t)BATCH * 512;
    bf16* r2   = p; p += (size_t)BATCH * 256;
    bf16* bw0t = p; p += 512 * 32;
    bf16* bw1t = p; p += 256 * 512;
    bf16* bw2t = p; p += 64 * 256;
    bf16* tw0t = p; p += 1024 * RLD;
    bf16* tw1t = p; p += 512 * 1024;
    bf16* tw2t = p; p += 256 * 512;
    float* out = (float*)d_out;

    WConvArgs wa;
    wa.src[0] = bw0;  wa.dst[0] = bw0t; wa.K[0] = 13;   wa.N[0] = 512;  wa.Kp[0] = 32;
    wa.src[1] = bw1;  wa.dst[1] = bw1t; wa.K[1] = 512;  wa.N[1] = 256;  wa.Kp[1] = 512;
    wa.src[2] = bw2;  wa.dst[2] = bw2t; wa.K[2] = 256;  wa.N[2] = 64;   wa.Kp[2] = 256;
    wa.src[3] = tw0;  wa.dst[3] = tw0t; wa.K[3] = 415;  wa.N[3] = 1024; wa.Kp[3] = RLD;
    wa.src[4] = tw1;  wa.dst[4] = tw1t; wa.K[4] = 1024; wa.N[4] = 512;  wa.Kp[4] = 1024;
    wa.src[5] = tw2;  wa.dst[5] = tw2t; wa.K[5] = 512;  wa.N[5] = 256;  wa.Kp[5] = 512;
    int tiles = 0;
    for (int w = 0; w < 6; ++w) {
        wa.t0[w] = tiles;
        tiles += (wa.Kp[w] >> 5) * (wa.N[w] >> 5);
    }
    wa.t0[6] = tiles;

    wconv_kernel<<<tiles, 256, 0, stream>>>(wa);

    // bottom MLP (layer 0: f32 dense staged+padded in-kernel; 64x64 tiles)
    gemm_bf16<32, 2, 2, 2, 2, true ><<<(BATCH / 64) * (512 / 64), 256, 0, stream>>>(
        dense, bw0t, bb0, h0, BATCH, 512, 32, 512);
    gemm_bf16<64, 2, 2, 2, 2, false><<<(BATCH / 64) * (256 / 64), 256, 0, stream>>>(
        h0, bw1t, bb1, h1, BATCH, 256, 512, 256);
    gemm_bf16<64, 2, 2, 2, 2, false><<<(BATCH / 64) * (64 / 64), 256, 0, stream>>>(
        h1, bw2t, bb2, R, BATCH, 64, 256, RLD);   // bot -> R[:, :64]

    interact_kernel<<<BATCH, 256, 0, stream>>>(cat_idx, tables, R);

    // top MLP
    gemm_bf16<64, 2, 2, 2, 2, false><<<(BATCH / 64) * (1024 / 64), 256, 0, stream>>>(
        R, tw0t, tb0, r0, BATCH, 1024, RLD, 1024);
    gemm_bf16<64, 2, 2, 2, 2, false><<<(BATCH / 64) * (512 / 64), 256, 0, stream>>>(
        r0, tw1t, tb1, r1, BATCH, 512, 1024, 512);
    gemm_bf16<64, 2, 2, 2, 2, false><<<(BATCH / 64) * (256 / 64), 256, 0, stream>>>(
        r1, tw2t, tb2, r2, BATCH, 256, 512, 256);
    top3_kernel<<<BATCH / 4, 256, 0, stream>>>(r2, tw3, tb3, out);
}